// Round 10
// baseline (626.493 us; speedup 1.0000x reference)
//
#include <hip/hip_runtime.h>
#include <cstdint>

// FracAttention: B=2, S=2048, D_MODEL=2048, H=16, DK=128
#define S_LEN   2048
#define DMODEL  2048
#define NHEADS  16
#define DK      128
#define MROWS   4096   // B*S

typedef _Float16 f16;
using f16x8 = __attribute__((ext_vector_type(8))) _Float16;
using f16x4 = __attribute__((ext_vector_type(4))) _Float16;
using f32x4 = __attribute__((ext_vector_type(4))) float;

typedef const __attribute__((address_space(1))) unsigned int gu32;
typedef __attribute__((address_space(3))) unsigned int lu32;

__device__ __forceinline__ void gl2lds16(const void* g, void* l) {
    // async global->LDS, 16 B per lane; LDS dest = wave-uniform base + lane*16
    __builtin_amdgcn_global_load_lds((gu32*)g, (lu32*)l, 16, 0, 0);
}

// ---------------------------------------------------------------------------
// fp32 -> fp16 convert. 4 float4 per thread (64 B/lane), 10240 blocks.
// (UNCHANGED from r7)
// ---------------------------------------------------------------------------
__global__ __launch_bounds__(256) void cvt_all(
    const float* __restrict__ q, const float* __restrict__ k,
    const float* __restrict__ v, const float* __restrict__ wq,
    const float* __restrict__ wk, const float* __restrict__ wv,
    const float* __restrict__ wo,
    f16* cq, f16* ck, f16* cv, f16* cwq, f16* cwk, f16* cwv, f16* cwo)
{
    const int b = blockIdx.x;
    const float* src; f16* dst; int base;
    if      (b <  2048) { src = q;  dst = cq;  base = b; }
    else if (b <  4096) { src = k;  dst = ck;  base = b - 2048; }
    else if (b <  6144) { src = v;  dst = cv;  base = b - 4096; }
    else if (b <  7168) { src = wq; dst = cwq; base = b - 6144; }
    else if (b <  8192) { src = wk; dst = cwk; base = b - 7168; }
    else if (b <  9216) { src = wv; dst = cwv; base = b - 8192; }
    else                { src = wo; dst = cwo; base = b - 9216; }
    const int i = base * 1024 + threadIdx.x;
#pragma unroll
    for (int u = 0; u < 4; ++u) {
        float4 x = ((const float4*)src)[i + u * 256];
        f16x4 o; o[0] = (f16)x.x; o[1] = (f16)x.y; o[2] = (f16)x.z; o[3] = (f16)x.w;
        ((f16x4*)dst)[i + u * 256] = o;
    }
}

// ---------------------------------------------------------------------------
// fp16 MFMA GEMM core (r7 winner: 128x128 tile, BK=64, 256 thr, 2x2 waves,
// 2 barriers/K-tile, gl2lds staging, 8-chunk XOR swizzle -> conflicts 0,
// natural blockIdx mapping).
// r9 POST-MORTEM (LDS_Block_Size=98304): static __shared__ inside a template
// gets a SEPARATE allocation per instantiation in the same kernel -- three
// MODE branches tripled LDS to 96 KB, occupancy 5 -> 1 block/CU, qkv 148->243.
// FIX: LDS buffers are declared ONCE in the __global__ caller and passed in.
// Epilogue stays compile-time specialized (MODE template); mode 2 (VT) packs
// 4 per-reg stores into one f16x4 (r9 measured WRITE_SIZE exactly 49152 =
// fully coalesced).
// mode 0: fp32 out [M][N]
// mode 1: f16 out head-permuted  [B,H,S,DK]             (K)
// mode 2: f16 out head-permuted + transposed [B,H,DK,S] (V -> VT)
// mode 3: f16 out head-permuted, scaled by sa[h]/max(sb[h],1)  (Q)
// ---------------------------------------------------------------------------
template<int MODE>
__device__ __forceinline__ void gemm_core(
    const f16* __restrict__ A, const f16* __restrict__ W,
    const float* __restrict__ bias, void* __restrict__ Cout,
    const float* __restrict__ sa, const float* __restrict__ sb,
    f16* __restrict__ As, f16* __restrict__ Bs)
{
    const int tid = threadIdx.x;
    const int bm = blockIdx.y * 128;
    const int bn = blockIdx.x * 128;
    const int wid = tid >> 6;
    const int ln = tid & 15;
    const int quad = (tid & 63) >> 4;
    const int wm = (wid >> 1) * 64;
    const int wn = (wid & 1) * 64;
    const int K = DMODEL, N = DMODEL;

    f32x4 acc[4][4];
#pragma unroll
    for (int i = 0; i < 4; ++i)
#pragma unroll
        for (int j = 0; j < 4; ++j)
            acc[i][j] = (f32x4){0.f, 0.f, 0.f, 0.f};

    // staging: thread t -> row (t>>3)+u*32, chunk (t&7); source pre-swizzled
    // by row key (t>>3)&7 (LDS dest linear, m104).
    const int srow = tid >> 3;                                  // 0..31
    const int schk = ((tid & 7) ^ ((tid >> 3) & 7)) * 8;        // f16 offset
    const f16* ga = A + (size_t)(bm + srow) * K + schk;
    const f16* gb = W + (size_t)(bn + srow) * K + schk;

    for (int k0 = 0; k0 < K; k0 += 64) {
        __syncthreads();
#pragma unroll
        for (int u = 0; u < 4; ++u)
            gl2lds16(ga + k0 + (size_t)(u * 32) * K, As + u * 2048 + tid * 8);
#pragma unroll
        for (int u = 0; u < 4; ++u)
            gl2lds16(gb + k0 + (size_t)(u * 32) * K, Bs + u * 2048 + tid * 8);
        __syncthreads();

#pragma unroll
        for (int kq = 0; kq < 2; ++kq) {
            f16x8 af[4], bf[4];
            const int rc = ((kq * 4 + quad) ^ (ln & 7)) * 8;    // swizzled chunk
#pragma unroll
            for (int i = 0; i < 4; ++i)
                af[i] = *(const f16x8*)&As[(wm + i * 16 + ln) * 64 + rc];
#pragma unroll
            for (int j = 0; j < 4; ++j)
                bf[j] = *(const f16x8*)&Bs[(wn + j * 16 + ln) * 64 + rc];
#pragma unroll
            for (int i = 0; i < 4; ++i)
#pragma unroll
                for (int j = 0; j < 4; ++j)
                    acc[i][j] = __builtin_amdgcn_mfma_f32_16x16x32_f16(
                        af[i], bf[j], acc[i][j], 0, 0, 0);
        }
    }

    // epilogue (compile-time specialized): C/D layout col=lane&15,
    // row=quad*4+reg.
#pragma unroll
    for (int j = 0; j < 4; ++j) {
        const int n = bn + wn + j * 16 + ln;
        const float bn_ = bias[n];
        const int h = n >> 7;           // n / DK
        const int d = n & (DK - 1);
        float scq = 1.0f;
        if constexpr (MODE == 3) scq = sa[h] / fmaxf(sb[h], 1.0f);
#pragma unroll
        for (int i = 0; i < 4; ++i) {
            const int m0 = bm + wm + i * 16 + quad * 4;   // reg adds 0..3
            if constexpr (MODE == 0) {
#pragma unroll
                for (int reg = 0; reg < 4; ++reg)
                    ((float*)Cout)[(size_t)(m0 + reg) * N + n] =
                        acc[i][j][reg] + bn_;
            } else if constexpr (MODE == 2) {
                // VT [B,H,DK,S]: 4 regs -> 4 consecutive ss -> one f16x4
                const int bb = m0 >> 11;
                const int ss = m0 & (S_LEN - 1);          // multiple of 4
                f16x4 o;
#pragma unroll
                for (int reg = 0; reg < 4; ++reg)
                    o[reg] = (f16)(acc[i][j][reg] + bn_);
                *(f16x4*)&((f16*)Cout)[
                    (((size_t)(bb * NHEADS + h) * DK + d) * S_LEN + ss)] = o;
            } else {
                // [B,H,S,DK]: reg -> ss+1 -> stride DK
                const int bb = m0 >> 11;
                const int ss = m0 & (S_LEN - 1);
                f16* dst = (f16*)Cout +
                    (((size_t)(bb * NHEADS + h) * S_LEN + ss) * DK + d);
#pragma unroll
                for (int reg = 0; reg < 4; ++reg) {
                    float v = acc[i][j][reg] + bn_;
                    if constexpr (MODE == 3) v *= scq;
                    dst[reg * DK] = (f16)v;
                }
            }
        }
    }
}

__global__ __launch_bounds__(256, 5) void qkv_gemm(
    const f16* Aq, const f16* Ak, const f16* Av,
    const f16* Wq, const f16* Wk, const f16* Wv,
    const float* bq, const float* bk, const float* bv,
    f16* Oq, f16* Ok, f16* Ov, const float* sa, const float* sb)
{
    // ONE shared allocation for all three MODE branches (r9 fix).
    __shared__ f16 As[128 * 64];   // 16 KB
    __shared__ f16 Bs[128 * 64];   // 16 KB
    const int z = blockIdx.z;
    if (z == 0)      gemm_core<3>(Aq, Wq, bq, (void*)Oq, sa, sb, As, Bs);
    else if (z == 1) gemm_core<1>(Ak, Wk, bk, (void*)Ok, nullptr, nullptr, As, Bs);
    else             gemm_core<2>(Av, Wv, bv, (void*)Ov, nullptr, nullptr, As, Bs);
}

__global__ __launch_bounds__(256) void out_gemm(
    const f16* A, const f16* W, const float* bias, float* O)
{
    __shared__ f16 As[128 * 64];
    __shared__ f16 Bs[128 * 64];
    gemm_core<0>(A, W, bias, (void*)O, nullptr, nullptr, As, Bs);
}

// ---------------------------------------------------------------------------
// Flash attention v6 (UNCHANGED from r6/r7): K double-buffered + counted-
// vmcnt pipeline; T2 swizzles + setprio; XCD bh-chunk swizzle.
// ---------------------------------------------------------------------------
__global__ __launch_bounds__(256, 2) void flash_v6(
    const f16* __restrict__ Qg, const f16* __restrict__ Kg,
    const f16* __restrict__ VTg, f16* __restrict__ AO)
{
    __shared__ f16 Ks[2][4 * 64 * 32];  // dbuf: [kb][kc][c][32]  32 KB
    __shared__ f16 Vs[2 * 128 * 32];    // [cc][d][32]            16 KB
    __shared__ f16 Ps[2 * 128 * 32];    // [cc][q][32]            16 KB
    __shared__ float l_buf[2 * 128];    // [wc][q]                 1 KB

    const int tid = threadIdx.x;
    const int wid = tid >> 6;
    const int ln = tid & 15;
    const int quad = (tid & 63) >> 4;
    const int wq = wid & 1;
    const int wc = wid >> 1;

    // XCD chunk swizzle: 512 blocks, 64 consecutive per XCD.
    const int lin = blockIdx.x + (blockIdx.y << 4);
    const int swz = (lin & 7) * 64 + (lin >> 3);
    const int q0 = (swz & 15) * 128;
    const int bh = swz >> 4;

    const int koff = (quad ^ ((ln >> 1) & 3)) * 8;                 // read, b128
    const int soff_sw = ((tid & 3) ^ ((tid >> 3) & 3)) * 8;        // staging src

    f16x8 qf[4][4];
    const f16* Qbase = Qg + ((size_t)bh * S_LEN + q0 + wq * 64) * DK;
#pragma unroll
    for (int nt = 0; nt < 4; ++nt)
#pragma unroll
        for (int kc = 0; kc < 4; ++kc)
            qf[nt][kc] = *(const f16x8*)(Qbase + (size_t)(nt * 16 + ln) * DK
                                         + kc * 32 + quad * 8);

    f32x4 o[4][4];
    float lp[4] = {0.f, 0.f, 0.f, 0.f};
#pragma unroll
    for (int i = 0; i < 4; ++i)
#pragma unroll
        for (int j = 0; j < 4; ++j)
            o[i][j] = (f32x4){0.f, 0.f, 0.f, 0.f};

    const f16* Kgb = Kg + (size_t)bh * S_LEN * DK;
    const f16* Vgb = VTg + (size_t)bh * DK * S_LEN;
    const int srow = tid >> 2;

    // prologue: stage K(0) into Ks[0]
#pragma unroll
    for (int j = 0; j < 4; ++j)
        gl2lds16(Kgb + (size_t)(srow)*DK + j * 32 + soff_sw,
                 &Ks[0][j * 2048 + tid * 8]);

    for (int kt = 0; kt < S_LEN / 64; ++kt) {
        asm volatile("s_waitcnt lgkmcnt(0)" ::: "memory");
        __builtin_amdgcn_s_barrier();
        __builtin_amdgcn_sched_barrier(0);

        // issue V(kt)
#pragma unroll
        for (int j = 0; j < 4; ++j)
            gl2lds16(Vgb + (size_t)(srow + (j & 1) * 64) * S_LEN
                         + kt * 64 + (j >> 1) * 32 + soff_sw,
                     Vs + (j >> 1) * 4096 + (j & 1) * 2048 + tid * 8);

        // K(kt) ready (retire all but the 4 V loads just issued)
        asm volatile("s_waitcnt vmcnt(4)" ::: "memory");
        __builtin_amdgcn_s_barrier();
        __builtin_amdgcn_sched_barrier(0);

        const f16* Kb = &Ks[kt & 1][0];
        f32x4 s[2][4];
#pragma unroll
        for (int mt = 0; mt < 2; ++mt)
#pragma unroll
            for (int nt = 0; nt < 4; ++nt)
                s[mt][nt] = (f32x4){0.f, 0.f, 0.f, 0.f};
        __builtin_amdgcn_s_setprio(1);
#pragma unroll
        for (int kc = 0; kc < 4; ++kc) {
            f16x8 kf0 = *(const f16x8*)&Kb[kc * 2048 + (wc * 32 + ln) * 32 + koff];
            f16x8 kf1 = *(const f16x8*)&Kb[kc * 2048 + (wc * 32 + 16 + ln) * 32 + koff];
#pragma unroll
            for (int nt = 0; nt < 4; ++nt) {
                s[0][nt] = __builtin_amdgcn_mfma_f32_16x16x32_f16(kf0, qf[nt][kc], s[0][nt], 0, 0, 0);
                s[1][nt] = __builtin_amdgcn_mfma_f32_16x16x32_f16(kf1, qf[nt][kc], s[1][nt], 0, 0, 0);
            }
        }
        __builtin_amdgcn_s_setprio(0);

        // issue K(kt+1) into the OTHER K buffer
        if (kt + 1 < S_LEN / 64) {
#pragma unroll
            for (int j = 0; j < 4; ++j)
                gl2lds16(Kgb + (size_t)((kt + 1) * 64 + srow) * DK + j * 32 + soff_sw,
                         &Ks[(kt + 1) & 1][j * 2048 + tid * 8]);
        }

        // exp (no max-sub), in-lane l partials, swizzled vectorized P write
#pragma unroll
        for (int mt = 0; mt < 2; ++mt) {
#pragma unroll
            for (int nt = 0; nt < 4; ++nt) {
                const float p0 = __expf(s[mt][nt][0]);
                const float p1 = __expf(s[mt][nt][1]);
                const float p2 = __expf(s[mt][nt][2]);
                const float p3 = __expf(s[mt][nt][3]);
                lp[nt] += (p0 + p1) + (p2 + p3);
                f16x4 pk;
                pk[0] = (f16)p0; pk[1] = (f16)p1; pk[2] = (f16)p2; pk[3] = (f16)p3;
                const int pchunk = ((mt * 2 + (quad >> 1)) ^ ((ln >> 1) & 3)) * 8
                                   + (quad & 1) * 4;
                *(f16x4*)&Ps[wc * 4096 + (wq * 64 + nt * 16 + ln) * 32 + pchunk] = pk;
            }
        }

        // V(kt) ready (K(kt+1) stays in flight); P visible after lgkm0+bar
        if (kt + 1 < S_LEN / 64) asm volatile("s_waitcnt vmcnt(4)" ::: "memory");
        else                     asm volatile("s_waitcnt vmcnt(0)" ::: "memory");
        asm volatile("s_waitcnt lgkmcnt(0)" ::: "memory");
        __builtin_amdgcn_s_barrier();
        __builtin_amdgcn_sched_barrier(0);

        __builtin_amdgcn_s_setprio(1);
#pragma unroll
        for (int cc = 0; cc < 2; ++cc) {
            f16x8 pf[4];
#pragma unroll
            for (int mtq = 0; mtq < 4; ++mtq)
                pf[mtq] = *(const f16x8*)&Ps[cc * 4096 + (wq * 64 + mtq * 16 + ln) * 32 + koff];
#pragma unroll
            for (int ntd = 0; ntd < 4; ++ntd) {
                f16x8 vf = *(const f16x8*)&Vs[cc * 4096 + (wc * 64 + ntd * 16 + ln) * 32 + koff];
#pragma unroll
                for (int mtq = 0; mtq < 4; ++mtq)
                    o[mtq][ntd] = __builtin_amdgcn_mfma_f32_16x16x32_f16(
                        pf[mtq], vf, o[mtq][ntd], 0, 0, 0);
            }
        }
        __builtin_amdgcn_s_setprio(0);
    }

    // finalize l: reduce over quads (c-spread), publish per (wc, q)
#pragma unroll
    for (int nt = 0; nt < 4; ++nt) {
        float v = lp[nt];
        v += __shfl_xor(v, 16, 64);
        v += __shfl_xor(v, 32, 64);
        lp[nt] = v;
    }
    __syncthreads();
    if (quad == 0) {
#pragma unroll
        for (int nt = 0; nt < 4; ++nt)
            l_buf[wc * 128 + wq * 64 + nt * 16 + ln] = lp[nt];
    }
    __syncthreads();

    // epilogue: AO[b][s][h*DK + d] = o / l
    const int b = bh >> 4;
    const int h = bh & (NHEADS - 1);
#pragma unroll
    for (int mtq = 0; mtq < 4; ++mtq) {
#pragma unroll
        for (int reg = 0; reg < 4; ++reg) {
            const int ql = wq * 64 + mtq * 16 + quad * 4 + reg;
            const float inv = 1.0f / (l_buf[ql] + l_buf[128 + ql]);
            f16* dst = AO + ((size_t)b * S_LEN + q0 + ql) * DMODEL + h * DK + wc * 64;
#pragma unroll
            for (int ntd = 0; ntd < 4; ++ntd)
                dst[ntd * 16 + ln] = (f16)(o[mtq][ntd][reg] * inv);
        }
    }
}

// ---------------------------------------------------------------------------
// Buffer plan (race-free, r2 lesson): Kh/VT live in d_out (dead until
// out_gemm, which runs after flash and fully overwrites it). AOh aliases c_v
// (cross-launch only). No output of any launch aliases a same-launch input.
// ---------------------------------------------------------------------------
extern "C" void kernel_launch(void* const* d_in, const int* in_sizes, int n_in,
                              void* d_out, int out_size, void* d_ws, size_t ws_size,
                              hipStream_t stream)
{
    (void)in_sizes; (void)n_in; (void)out_size; (void)ws_size;
    const float* query = (const float*)d_in[0];
    const float* key_  = (const float*)d_in[1];
    const float* value = (const float*)d_in[2];
    const float* w_q = (const float*)d_in[3];
    const float* b_q = (const float*)d_in[4];
    const float* w_k = (const float*)d_in[5];
    const float* b_k = (const float*)d_in[6];
    const float* w_v = (const float*)d_in[7];
    const float* b_v = (const float*)d_in[8];
    const float* w_o = (const float*)d_in[9];
    const float* b_o = (const float*)d_in[10];
    const float* s_alpha = (const float*)d_in[11];
    const float* s_beta  = (const float*)d_in[12];
    float* out = (float*)d_out;

    const size_t T = (size_t)MROWS * DMODEL;    // 8,388,608
    const size_t Wn = (size_t)DMODEL * DMODEL;  // 4,194,304
    f16* base = (f16*)d_ws;
    f16* c_q = base;
    f16* c_k = base + T;
    f16* c_v = base + 2 * T;      // later reused as AOh (cross-launch, safe)
    f16* Qh  = base + 3 * T;
    f16* wq16 = base + 4 * T;
    f16* wk16 = wq16 + Wn;
    f16* wv16 = wk16 + Wn;
    f16* wo16 = wv16 + Wn;
    f16* Kh  = (f16*)d_out;       // 16MB: first half of d_out
    f16* VT  = Kh + T;            // 16MB: second half of d_out
    f16* AOh = c_v;

    cvt_all<<<dim3(10240), dim3(256), 0, stream>>>(
        query, key_, value, w_q, w_k, w_v, w_o,
        c_q, c_k, c_v, wq16, wk16, wv16, wo16);

    dim3 qkv_grid(DMODEL / 128, MROWS / 128, 3);  // (16, 32, 3) = 1536 blocks
    qkv_gemm<<<qkv_grid, dim3(256), 0, stream>>>(c_q, c_k, c_v, wq16, wk16, wv16,
                                                 b_q, b_k, b_v, Qh, Kh, VT,
                                                 s_alpha, s_beta);

    dim3 flash_grid(S_LEN / 128, 2 * NHEADS);     // (16, 32)
    flash_v6<<<flash_grid, dim3(256), 0, stream>>>(Qh, Kh, VT, AOh);

    dim3 out_grid(DMODEL / 128, MROWS / 128);     // (16, 32)
    out_gemm<<<out_grid, dim3(256), 0, stream>>>(AOh, wo16, b_o, out);
}

// Round 11
// 451.774 us; speedup vs baseline: 1.3867x; 1.3867x over previous
//
#include <hip/hip_runtime.h>
#include <cstdint>

// FracAttention: B=2, S=2048, D_MODEL=2048, H=16, DK=128
#define S_LEN   2048
#define DMODEL  2048
#define NHEADS  16
#define DK      128
#define MROWS   4096   // B*S

typedef _Float16 f16;
using f16x8 = __attribute__((ext_vector_type(8))) _Float16;
using f16x4 = __attribute__((ext_vector_type(4))) _Float16;
using f32x4 = __attribute__((ext_vector_type(4))) float;

typedef const __attribute__((address_space(1))) unsigned int gu32;
typedef __attribute__((address_space(3))) unsigned int lu32;

__device__ __forceinline__ void gl2lds16(const void* g, void* l) {
    // async global->LDS, 16 B per lane; LDS dest = wave-uniform base + lane*16
    __builtin_amdgcn_global_load_lds((gu32*)g, (lu32*)l, 16, 0, 0);
}

// ---------------------------------------------------------------------------
// fp32 -> fp16 convert. 4 float4 per thread (64 B/lane), 10240 blocks.
// (UNCHANGED from r7)
// ---------------------------------------------------------------------------
__global__ __launch_bounds__(256) void cvt_all(
    const float* __restrict__ q, const float* __restrict__ k,
    const float* __restrict__ v, const float* __restrict__ wq,
    const float* __restrict__ wk, const float* __restrict__ wv,
    const float* __restrict__ wo,
    f16* cq, f16* ck, f16* cv, f16* cwq, f16* cwk, f16* cwv, f16* cwo)
{
    const int b = blockIdx.x;
    const float* src; f16* dst; int base;
    if      (b <  2048) { src = q;  dst = cq;  base = b; }
    else if (b <  4096) { src = k;  dst = ck;  base = b - 2048; }
    else if (b <  6144) { src = v;  dst = cv;  base = b - 4096; }
    else if (b <  7168) { src = wq; dst = cwq; base = b - 6144; }
    else if (b <  8192) { src = wk; dst = cwk; base = b - 7168; }
    else if (b <  9216) { src = wv; dst = cwv; base = b - 8192; }
    else                { src = wo; dst = cwo; base = b - 9216; }
    const int i = base * 1024 + threadIdx.x;
#pragma unroll
    for (int u = 0; u < 4; ++u) {
        float4 x = ((const float4*)src)[i + u * 256];
        f16x4 o; o[0] = (f16)x.x; o[1] = (f16)x.y; o[2] = (f16)x.z; o[3] = (f16)x.w;
        ((f16x4*)dst)[i + u * 256] = o;
    }
}

// ---------------------------------------------------------------------------
// fp16 MFMA GEMM core (r7 winner: 128x128 tile, BK=64, 256 thr, 2x2 waves,
// 2 barriers/K-tile, gl2lds staging, 8-chunk XOR swizzle -> conflicts 0,
// natural blockIdx mapping).
// r9 lesson: static __shared__ inside a template = separate allocation per
// instantiation (3x LDS) -> buffers declared ONCE in caller, passed in.
// r10 lesson: __launch_bounds__ 2nd arg (min waves/EU) over-constrained the
// register allocator (VGPR 48 < the 64-VGPR accumulator -> scratch spills,
// WRITE_SIZE 614 MB, MfmaUtil 1.5%). Plain __launch_bounds__(256) as in r7.
// mode 0: fp32 out [M][N]
// mode 1: f16 out head-permuted  [B,H,S,DK]             (K)
// mode 2: f16 out head-permuted + transposed [B,H,DK,S] (V -> VT)
// mode 3: f16 out head-permuted, scaled by sa[h]/max(sb[h],1)  (Q)
// ---------------------------------------------------------------------------
template<int MODE>
__device__ __forceinline__ void gemm_core(
    const f16* __restrict__ A, const f16* __restrict__ W,
    const float* __restrict__ bias, void* __restrict__ Cout,
    const float* __restrict__ sa, const float* __restrict__ sb,
    f16* __restrict__ As, f16* __restrict__ Bs)
{
    const int tid = threadIdx.x;
    const int bm = blockIdx.y * 128;
    const int bn = blockIdx.x * 128;
    const int wid = tid >> 6;
    const int ln = tid & 15;
    const int quad = (tid & 63) >> 4;
    const int wm = (wid >> 1) * 64;
    const int wn = (wid & 1) * 64;
    const int K = DMODEL, N = DMODEL;

    f32x4 acc[4][4];
#pragma unroll
    for (int i = 0; i < 4; ++i)
#pragma unroll
        for (int j = 0; j < 4; ++j)
            acc[i][j] = (f32x4){0.f, 0.f, 0.f, 0.f};

    // staging: thread t -> row (t>>3)+u*32, chunk (t&7); source pre-swizzled
    // by row key (t>>3)&7 (LDS dest linear, m104).
    const int srow = tid >> 3;                                  // 0..31
    const int schk = ((tid & 7) ^ ((tid >> 3) & 7)) * 8;        // f16 offset
    const f16* ga = A + (size_t)(bm + srow) * K + schk;
    const f16* gb = W + (size_t)(bn + srow) * K + schk;

    for (int k0 = 0; k0 < K; k0 += 64) {
        __syncthreads();
#pragma unroll
        for (int u = 0; u < 4; ++u)
            gl2lds16(ga + k0 + (size_t)(u * 32) * K, As + u * 2048 + tid * 8);
#pragma unroll
        for (int u = 0; u < 4; ++u)
            gl2lds16(gb + k0 + (size_t)(u * 32) * K, Bs + u * 2048 + tid * 8);
        __syncthreads();

#pragma unroll
        for (int kq = 0; kq < 2; ++kq) {
            f16x8 af[4], bf[4];
            const int rc = ((kq * 4 + quad) ^ (ln & 7)) * 8;    // swizzled chunk
#pragma unroll
            for (int i = 0; i < 4; ++i)
                af[i] = *(const f16x8*)&As[(wm + i * 16 + ln) * 64 + rc];
#pragma unroll
            for (int j = 0; j < 4; ++j)
                bf[j] = *(const f16x8*)&Bs[(wn + j * 16 + ln) * 64 + rc];
#pragma unroll
            for (int i = 0; i < 4; ++i)
#pragma unroll
                for (int j = 0; j < 4; ++j)
                    acc[i][j] = __builtin_amdgcn_mfma_f32_16x16x32_f16(
                        af[i], bf[j], acc[i][j], 0, 0, 0);
        }
    }

    // epilogue (compile-time specialized): C/D layout col=lane&15,
    // row=quad*4+reg.
#pragma unroll
    for (int j = 0; j < 4; ++j) {
        const int n = bn + wn + j * 16 + ln;
        const float bn_ = bias[n];
        const int h = n >> 7;           // n / DK
        const int d = n & (DK - 1);
        float scq = 1.0f;
        if constexpr (MODE == 3) scq = sa[h] / fmaxf(sb[h], 1.0f);
#pragma unroll
        for (int i = 0; i < 4; ++i) {
            const int m0 = bm + wm + i * 16 + quad * 4;   // reg adds 0..3
            if constexpr (MODE == 0) {
#pragma unroll
                for (int reg = 0; reg < 4; ++reg)
                    ((float*)Cout)[(size_t)(m0 + reg) * N + n] =
                        acc[i][j][reg] + bn_;
            } else if constexpr (MODE == 2) {
                // VT [B,H,DK,S]: 4 regs -> 4 consecutive ss -> one f16x4
                const int bb = m0 >> 11;
                const int ss = m0 & (S_LEN - 1);          // multiple of 4
                f16x4 o;
#pragma unroll
                for (int reg = 0; reg < 4; ++reg)
                    o[reg] = (f16)(acc[i][j][reg] + bn_);
                *(f16x4*)&((f16*)Cout)[
                    (((size_t)(bb * NHEADS + h) * DK + d) * S_LEN + ss)] = o;
            } else {
                // [B,H,S,DK]: reg -> ss+1 -> stride DK
                const int bb = m0 >> 11;
                const int ss = m0 & (S_LEN - 1);
                f16* dst = (f16*)Cout +
                    (((size_t)(bb * NHEADS + h) * S_LEN + ss) * DK + d);
#pragma unroll
                for (int reg = 0; reg < 4; ++reg) {
                    float v = acc[i][j][reg] + bn_;
                    if constexpr (MODE == 3) v *= scq;
                    dst[reg * DK] = (f16)v;
                }
            }
        }
    }
}

__global__ __launch_bounds__(256) void qkv_gemm(
    const f16* Aq, const f16* Ak, const f16* Av,
    const f16* Wq, const f16* Wk, const f16* Wv,
    const float* bq, const float* bk, const float* bv,
    f16* Oq, f16* Ok, f16* Ov, const float* sa, const float* sb)
{
    // ONE shared allocation for all three MODE branches (r9 fix).
    __shared__ f16 As[128 * 64];   // 16 KB
    __shared__ f16 Bs[128 * 64];   // 16 KB
    const int z = blockIdx.z;
    if (z == 0)      gemm_core<3>(Aq, Wq, bq, (void*)Oq, sa, sb, As, Bs);
    else if (z == 1) gemm_core<1>(Ak, Wk, bk, (void*)Ok, nullptr, nullptr, As, Bs);
    else             gemm_core<2>(Av, Wv, bv, (void*)Ov, nullptr, nullptr, As, Bs);
}

__global__ __launch_bounds__(256) void out_gemm(
    const f16* A, const f16* W, const float* bias, float* O)
{
    __shared__ f16 As[128 * 64];
    __shared__ f16 Bs[128 * 64];
    gemm_core<0>(A, W, bias, (void*)O, nullptr, nullptr, As, Bs);
}

// ---------------------------------------------------------------------------
// Flash attention v6 (UNCHANGED from r6/r7): K double-buffered + counted-
// vmcnt pipeline; T2 swizzles + setprio; XCD bh-chunk swizzle.
// ---------------------------------------------------------------------------
__global__ __launch_bounds__(256, 2) void flash_v6(
    const f16* __restrict__ Qg, const f16* __restrict__ Kg,
    const f16* __restrict__ VTg, f16* __restrict__ AO)
{
    __shared__ f16 Ks[2][4 * 64 * 32];  // dbuf: [kb][kc][c][32]  32 KB
    __shared__ f16 Vs[2 * 128 * 32];    // [cc][d][32]            16 KB
    __shared__ f16 Ps[2 * 128 * 32];    // [cc][q][32]            16 KB
    __shared__ float l_buf[2 * 128];    // [wc][q]                 1 KB

    const int tid = threadIdx.x;
    const int wid = tid >> 6;
    const int ln = tid & 15;
    const int quad = (tid & 63) >> 4;
    const int wq = wid & 1;
    const int wc = wid >> 1;

    // XCD chunk swizzle: 512 blocks, 64 consecutive per XCD.
    const int lin = blockIdx.x + (blockIdx.y << 4);
    const int swz = (lin & 7) * 64 + (lin >> 3);
    const int q0 = (swz & 15) * 128;
    const int bh = swz >> 4;

    const int koff = (quad ^ ((ln >> 1) & 3)) * 8;                 // read, b128
    const int soff_sw = ((tid & 3) ^ ((tid >> 3) & 3)) * 8;        // staging src

    f16x8 qf[4][4];
    const f16* Qbase = Qg + ((size_t)bh * S_LEN + q0 + wq * 64) * DK;
#pragma unroll
    for (int nt = 0; nt < 4; ++nt)
#pragma unroll
        for (int kc = 0; kc < 4; ++kc)
            qf[nt][kc] = *(const f16x8*)(Qbase + (size_t)(nt * 16 + ln) * DK
                                         + kc * 32 + quad * 8);

    f32x4 o[4][4];
    float lp[4] = {0.f, 0.f, 0.f, 0.f};
#pragma unroll
    for (int i = 0; i < 4; ++i)
#pragma unroll
        for (int j = 0; j < 4; ++j)
            o[i][j] = (f32x4){0.f, 0.f, 0.f, 0.f};

    const f16* Kgb = Kg + (size_t)bh * S_LEN * DK;
    const f16* Vgb = VTg + (size_t)bh * DK * S_LEN;
    const int srow = tid >> 2;

    // prologue: stage K(0) into Ks[0]
#pragma unroll
    for (int j = 0; j < 4; ++j)
        gl2lds16(Kgb + (size_t)(srow)*DK + j * 32 + soff_sw,
                 &Ks[0][j * 2048 + tid * 8]);

    for (int kt = 0; kt < S_LEN / 64; ++kt) {
        asm volatile("s_waitcnt lgkmcnt(0)" ::: "memory");
        __builtin_amdgcn_s_barrier();
        __builtin_amdgcn_sched_barrier(0);

        // issue V(kt)
#pragma unroll
        for (int j = 0; j < 4; ++j)
            gl2lds16(Vgb + (size_t)(srow + (j & 1) * 64) * S_LEN
                         + kt * 64 + (j >> 1) * 32 + soff_sw,
                     Vs + (j >> 1) * 4096 + (j & 1) * 2048 + tid * 8);

        // K(kt) ready (retire all but the 4 V loads just issued)
        asm volatile("s_waitcnt vmcnt(4)" ::: "memory");
        __builtin_amdgcn_s_barrier();
        __builtin_amdgcn_sched_barrier(0);

        const f16* Kb = &Ks[kt & 1][0];
        f32x4 s[2][4];
#pragma unroll
        for (int mt = 0; mt < 2; ++mt)
#pragma unroll
            for (int nt = 0; nt < 4; ++nt)
                s[mt][nt] = (f32x4){0.f, 0.f, 0.f, 0.f};
        __builtin_amdgcn_s_setprio(1);
#pragma unroll
        for (int kc = 0; kc < 4; ++kc) {
            f16x8 kf0 = *(const f16x8*)&Kb[kc * 2048 + (wc * 32 + ln) * 32 + koff];
            f16x8 kf1 = *(const f16x8*)&Kb[kc * 2048 + (wc * 32 + 16 + ln) * 32 + koff];
#pragma unroll
            for (int nt = 0; nt < 4; ++nt) {
                s[0][nt] = __builtin_amdgcn_mfma_f32_16x16x32_f16(kf0, qf[nt][kc], s[0][nt], 0, 0, 0);
                s[1][nt] = __builtin_amdgcn_mfma_f32_16x16x32_f16(kf1, qf[nt][kc], s[1][nt], 0, 0, 0);
            }
        }
        __builtin_amdgcn_s_setprio(0);

        // issue K(kt+1) into the OTHER K buffer
        if (kt + 1 < S_LEN / 64) {
#pragma unroll
            for (int j = 0; j < 4; ++j)
                gl2lds16(Kgb + (size_t)((kt + 1) * 64 + srow) * DK + j * 32 + soff_sw,
                         &Ks[(kt + 1) & 1][j * 2048 + tid * 8]);
        }

        // exp (no max-sub), in-lane l partials, swizzled vectorized P write
#pragma unroll
        for (int mt = 0; mt < 2; ++mt) {
#pragma unroll
            for (int nt = 0; nt < 4; ++nt) {
                const float p0 = __expf(s[mt][nt][0]);
                const float p1 = __expf(s[mt][nt][1]);
                const float p2 = __expf(s[mt][nt][2]);
                const float p3 = __expf(s[mt][nt][3]);
                lp[nt] += (p0 + p1) + (p2 + p3);
                f16x4 pk;
                pk[0] = (f16)p0; pk[1] = (f16)p1; pk[2] = (f16)p2; pk[3] = (f16)p3;
                const int pchunk = ((mt * 2 + (quad >> 1)) ^ ((ln >> 1) & 3)) * 8
                                   + (quad & 1) * 4;
                *(f16x4*)&Ps[wc * 4096 + (wq * 64 + nt * 16 + ln) * 32 + pchunk] = pk;
            }
        }

        // V(kt) ready (K(kt+1) stays in flight); P visible after lgkm0+bar
        if (kt + 1 < S_LEN / 64) asm volatile("s_waitcnt vmcnt(4)" ::: "memory");
        else                     asm volatile("s_waitcnt vmcnt(0)" ::: "memory");
        asm volatile("s_waitcnt lgkmcnt(0)" ::: "memory");
        __builtin_amdgcn_s_barrier();
        __builtin_amdgcn_sched_barrier(0);

        __builtin_amdgcn_s_setprio(1);
#pragma unroll
        for (int cc = 0; cc < 2; ++cc) {
            f16x8 pf[4];
#pragma unroll
            for (int mtq = 0; mtq < 4; ++mtq)
                pf[mtq] = *(const f16x8*)&Ps[cc * 4096 + (wq * 64 + mtq * 16 + ln) * 32 + koff];
#pragma unroll
            for (int ntd = 0; ntd < 4; ++ntd) {
                f16x8 vf = *(const f16x8*)&Vs[cc * 4096 + (wc * 64 + ntd * 16 + ln) * 32 + koff];
#pragma unroll
                for (int mtq = 0; mtq < 4; ++mtq)
                    o[mtq][ntd] = __builtin_amdgcn_mfma_f32_16x16x32_f16(
                        pf[mtq], vf, o[mtq][ntd], 0, 0, 0);
            }
        }
        __builtin_amdgcn_s_setprio(0);
    }

    // finalize l: reduce over quads (c-spread), publish per (wc, q)
#pragma unroll
    for (int nt = 0; nt < 4; ++nt) {
        float v = lp[nt];
        v += __shfl_xor(v, 16, 64);
        v += __shfl_xor(v, 32, 64);
        lp[nt] = v;
    }
    __syncthreads();
    if (quad == 0) {
#pragma unroll
        for (int nt = 0; nt < 4; ++nt)
            l_buf[wc * 128 + wq * 64 + nt * 16 + ln] = lp[nt];
    }
    __syncthreads();

    // epilogue: AO[b][s][h*DK + d] = o / l
    const int b = bh >> 4;
    const int h = bh & (NHEADS - 1);
#pragma unroll
    for (int mtq = 0; mtq < 4; ++mtq) {
#pragma unroll
        for (int reg = 0; reg < 4; ++reg) {
            const int ql = wq * 64 + mtq * 16 + quad * 4 + reg;
            const float inv = 1.0f / (l_buf[ql] + l_buf[128 + ql]);
            f16* dst = AO + ((size_t)b * S_LEN + q0 + ql) * DMODEL + h * DK + wc * 64;
#pragma unroll
            for (int ntd = 0; ntd < 4; ++ntd)
                dst[ntd * 16 + ln] = (f16)(o[mtq][ntd][reg] * inv);
        }
    }
}

// ---------------------------------------------------------------------------
// Buffer plan (race-free, r2 lesson): Kh/VT live in d_out (dead until
// out_gemm, which runs after flash and fully overwrites it). AOh aliases c_v
// (cross-launch only). No output of any launch aliases a same-launch input.
// ---------------------------------------------------------------------------
extern "C" void kernel_launch(void* const* d_in, const int* in_sizes, int n_in,
                              void* d_out, int out_size, void* d_ws, size_t ws_size,
                              hipStream_t stream)
{
    (void)in_sizes; (void)n_in; (void)out_size; (void)ws_size;
    const float* query = (const float*)d_in[0];
    const float* key_  = (const float*)d_in[1];
    const float* value = (const float*)d_in[2];
    const float* w_q = (const float*)d_in[3];
    const float* b_q = (const float*)d_in[4];
    const float* w_k = (const float*)d_in[5];
    const float* b_k = (const float*)d_in[6];
    const float* w_v = (const float*)d_in[7];
    const float* b_v = (const float*)d_in[8];
    const float* w_o = (const float*)d_in[9];
    const float* b_o = (const float*)d_in[10];
    const float* s_alpha = (const float*)d_in[11];
    const float* s_beta  = (const float*)d_in[12];
    float* out = (float*)d_out;

    const size_t T = (size_t)MROWS * DMODEL;    // 8,388,608
    const size_t Wn = (size_t)DMODEL * DMODEL;  // 4,194,304
    f16* base = (f16*)d_ws;
    f16* c_q = base;
    f16* c_k = base + T;
    f16* c_v = base + 2 * T;      // later reused as AOh (cross-launch, safe)
    f16* Qh  = base + 3 * T;
    f16* wq16 = base + 4 * T;
    f16* wk16 = wq16 + Wn;
    f16* wv16 = wk16 + Wn;
    f16* wo16 = wv16 + Wn;
    f16* Kh  = (f16*)d_out;       // 16MB: first half of d_out
    f16* VT  = Kh + T;            // 16MB: second half of d_out
    f16* AOh = c_v;

    cvt_all<<<dim3(10240), dim3(256), 0, stream>>>(
        query, key_, value, w_q, w_k, w_v, w_o,
        c_q, c_k, c_v, wq16, wk16, wv16, wo16);

    dim3 qkv_grid(DMODEL / 128, MROWS / 128, 3);  // (16, 32, 3) = 1536 blocks
    qkv_gemm<<<qkv_grid, dim3(256), 0, stream>>>(c_q, c_k, c_v, wq16, wk16, wv16,
                                                 b_q, b_k, b_v, Qh, Kh, VT,
                                                 s_alpha, s_beta);

    dim3 flash_grid(S_LEN / 128, 2 * NHEADS);     // (16, 32)
    flash_v6<<<flash_grid, dim3(256), 0, stream>>>(Qh, Kh, VT, AOh);

    dim3 out_grid(DMODEL / 128, MROWS / 128);     // (16, 32)
    out_gemm<<<out_grid, dim3(256), 0, stream>>>(AOh, wo16, b_o, out);
}